// Round 2
// baseline (619.936 us; speedup 1.0000x reference)
//
#include <hip/hip_runtime.h>
#include <cstdint>
#include <cmath>

// Problem constants (from reference): T=512, N=32, C=5000, S=100
#define Tt   512
#define Nb   32
#define Cc   5000
#define Sm   100
#define Lw   201              // 2*S+1 extended lattice width
#define Lpad 256              // padded lattice width for em table (shift-friendly)
#define NEGV (-1e30f)

// ---------------------------------------------------------------------------
// Kernel 1: full-machine emission gather.
//   em[n][t][l] = lp[t][n][ext[n][l]]  for l < 2*tlen[n]+1, else NEGV
// One block per (n,t): 16384 blocks x 256 threads -> all 256 CUs issue the
// scattered 4B reads; fetch (~160-210MB of 128B lines) runs at machine BW.
// ---------------------------------------------------------------------------
__global__ __launch_bounds__(256, 1)
void ctc_gather_kernel(const float* __restrict__ lp,    // [T,N,C]
                       const int*   __restrict__ tgt,   // [N,S]
                       const int*   __restrict__ tlen,  // [N]
                       float*       __restrict__ em)    // [N,T,Lpad]
{
    const int bid = blockIdx.x;          // = n*Tt + t
    const int n   = bid >> 9;            // Tt = 512 = 2^9
    const int t   = bid & (Tt - 1);
    const int l   = threadIdx.x;

    const int Lact = 2 * tlen[n] + 1;    // <= 201

    float v = NEGV;
    if (l < Lact) {
        int e = 0;                                        // blank column
        if (l & 1) e = tgt[n * Sm + ((l - 1) >> 1)];      // label column
        v = lp[((size_t)t * Nb + n) * Cc + e];
    }
    em[((size_t)bid << 8) | l] = v;      // (n*Tt+t)*Lpad + l, coalesced
}

// ---------------------------------------------------------------------------
// Kernel 2: sequential alpha recursion over the dense em table.
// One block per batch item; thread l owns lattice position l.
// Alpha double-buffered in LDS (1 barrier/step); em reads are contiguous
// 1KB rows, register-prefetched PF deep (statically indexed -> no scratch).
// ---------------------------------------------------------------------------
__global__ __launch_bounds__(256, 1)
void ctc_alpha_em_kernel(const float* __restrict__ em,    // [N,T,Lpad]
                         const int*   __restrict__ tgt,   // [N,S]
                         const int*   __restrict__ ilen,  // [N]
                         const int*   __restrict__ tlen,  // [N]
                         float*       __restrict__ per_loss) // [N]
{
    const int n = blockIdx.x;
    const int l = threadIdx.x;

    __shared__ float s_alpha[2][256];

    const int tl   = tlen[n];
    const int il   = ilen[n];
    const int Lact = 2 * tl + 1;
    const bool inL = (l < Lact);

    // allow alpha[l-2] transition: odd position whose label differs from the
    // label two lattice slots back (reference allow_skip)
    bool skip_ok = false;
    if ((l & 1) && l < Lw) {
        int j = (l - 1) >> 1;
        if (j >= 1) skip_ok = (tgt[n * Sm + j] != tgt[n * Sm + j - 1]);
        // j==0 (l==1): reference pads a2 with NEG; handled by the l>=2 guard.
    }

    const float* emn = em + ((size_t)n << 17);            // n * Tt * Lpad

    // ---- t = 0 init ----
    float em0   = emn[l];
    float alpha = NEGV;
    if (l == 0)                alpha = em0;
    else if (l == 1 && tl > 0) alpha = em0;
    if (!inL)                  alpha = NEGV;
    s_alpha[0][l] = alpha;

    // ---- register prefetch pipeline: em rows for t = 1..PF ----
    constexpr int PF = 8;
    float ebuf[PF];
#pragma unroll
    for (int i = 0; i < PF; ++i) {
        int t = 1 + i;
        ebuf[i] = (t < Tt) ? emn[(t << 8) | l] : NEGV;
    }
    __syncthreads();

    int cur = 0;
    for (int tb = 1; tb < Tt; tb += PF) {
#pragma unroll
        for (int i = 0; i < PF; ++i) {          // static ebuf index (rule #20)
            const int t = tb + i;
            if (t < Tt) {                       // block-uniform -> barrier-safe
                float e  = ebuf[i];
                int   tp = t + PF;
                if (tp < Tt) ebuf[i] = emn[(tp << 8) | l];   // prefetch ahead

                float a0  = alpha;
                float am1 = (l >= 1)            ? s_alpha[cur][l - 1] : NEGV;
                float am2 = (skip_ok && l >= 2) ? s_alpha[cur][l - 2] : NEGV;

                // logsumexp3 via sorted terms: max term contributes exactly 1.0
                // -> one v_exp_f32 saved vs the naive 3-exp form.
                float m   = fmaxf(fmaxf(a0, am1), am2);          // v_max3
                float mid = __builtin_amdgcn_fmed3f(a0, am1, am2); // v_med3
                float lo  = fminf(fminf(a0, am1), am2);          // v_min3
                float s   = 1.0f + __expf(mid - m) + __expf(lo - m);
                float nv  = m + __logf(s) + e;

                if (!inL)    nv = NEGV;          // pos_mask
                if (t >= il) nv = a0;            // freeze past input length

                alpha = nv;
                s_alpha[cur ^ 1][l] = nv;        // double buffer: 1 barrier/step
                __syncthreads();
                cur ^= 1;
            }
        }
    }

    // ---- per-n loss from final alpha ----
    if (l == 0) {
        int   last = 2 * tl;
        float ab   = s_alpha[cur][last];
        int   li   = last - 1; if (li < 0) li = 0;
        float al   = s_alpha[cur][li];
        float m    = fmaxf(ab, al);
        float ll   = m + __logf(__expf(ab - m) + __expf(al - m));
        float loss = -ll;
        if (!(isfinite(loss) && loss < 1e29f)) loss = 0.0f;   // zero_infinity
        int   d    = (tl >= 1) ? tl : 1;
        per_loss[n] = loss / (float)d;
    }
}

// ---------------------------------------------------------------------------
// Fallback (ws too small): fused recursion gathering lp directly (32 blocks).
// ---------------------------------------------------------------------------
__global__ __launch_bounds__(256, 1)
void ctc_alpha_fused_kernel(const float* __restrict__ lp,
                            const int*   __restrict__ tgt,
                            const int*   __restrict__ ilen,
                            const int*   __restrict__ tlen,
                            float*       __restrict__ per_loss)
{
    const int n = blockIdx.x;
    const int l = threadIdx.x;
    __shared__ float s_alpha[2][256];

    const int tl   = tlen[n];
    const int il   = ilen[n];
    const int Lact = 2 * tl + 1;
    const bool inL = (l < Lw) && (l < Lact);

    int  e = 0;
    bool skip_ok = false;
    if (l & 1) {
        int j = (l - 1) >> 1;
        if (j < Sm) {
            e = tgt[n * Sm + j];
            if (j >= 1) skip_ok = (e != tgt[n * Sm + j - 1]);
        }
    }

    const float* lpn     = lp + (size_t)n * Cc;
    const size_t strideT = (size_t)Nb * Cc;

    float em0   = lpn[e];
    float alpha = NEGV;
    if (l == 0)                alpha = em0;
    else if (l == 1 && tl > 0) alpha = em0;
    if (!inL)                  alpha = NEGV;
    s_alpha[0][l] = alpha;

    constexpr int PF = 8;
    float ebuf[PF];
#pragma unroll
    for (int i = 0; i < PF; ++i) {
        int t = 1 + i;
        ebuf[i] = (t < Tt) ? lpn[(size_t)t * strideT + e] : NEGV;
    }
    __syncthreads();

    int cur = 0;
    for (int tb = 1; tb < Tt; tb += PF) {
#pragma unroll
        for (int i = 0; i < PF; ++i) {
            const int t = tb + i;
            if (t < Tt) {
                float em = ebuf[i];
                int   tp = t + PF;
                if (tp < Tt) ebuf[i] = lpn[(size_t)tp * strideT + e];

                float a0  = alpha;
                float am1 = (l >= 1)            ? s_alpha[cur][l - 1] : NEGV;
                float am2 = (skip_ok && l >= 2) ? s_alpha[cur][l - 2] : NEGV;

                float m   = fmaxf(fmaxf(a0, am1), am2);
                float mid = __builtin_amdgcn_fmed3f(a0, am1, am2);
                float lo  = fminf(fminf(a0, am1), am2);
                float s   = 1.0f + __expf(mid - m) + __expf(lo - m);
                float nv  = m + __logf(s) + em;

                if (!inL)    nv = NEGV;
                if (t >= il) nv = a0;

                alpha = nv;
                s_alpha[cur ^ 1][l] = nv;
                __syncthreads();
                cur ^= 1;
            }
        }
    }

    if (l == 0) {
        int   last = 2 * tl;
        float ab   = s_alpha[cur][last];
        int   li   = last - 1; if (li < 0) li = 0;
        float al   = s_alpha[cur][li];
        float m    = fmaxf(ab, al);
        float ll   = m + __logf(__expf(ab - m) + __expf(al - m));
        float loss = -ll;
        if (!(isfinite(loss) && loss < 1e29f)) loss = 0.0f;
        int   d    = (tl >= 1) ? tl : 1;
        per_loss[n] = loss / (float)d;
    }
}

// Mean over N per-item losses -> scalar
__global__ void ctc_finalize_kernel(const float* __restrict__ per_loss,
                                    float* __restrict__ out)
{
    int i = threadIdx.x;
    float v = (i < Nb) ? per_loss[i] : 0.0f;
#pragma unroll
    for (int off = 32; off > 0; off >>= 1)
        v += __shfl_down(v, off, 64);
    if (i == 0) out[0] = v * (1.0f / Nb);
}

extern "C" void kernel_launch(void* const* d_in, const int* in_sizes, int n_in,
                              void* d_out, int out_size, void* d_ws, size_t ws_size,
                              hipStream_t stream)
{
    const float* lp   = (const float*)d_in[0];   // [T,N,C] f32
    const int*   tgt  = (const int*)  d_in[1];   // [N,S]   i32
    const int*   ilen = (const int*)  d_in[2];   // [N]     i32
    const int*   tlen = (const int*)  d_in[3];   // [N]     i32
    float*       out  = (float*)d_out;           // scalar f32

    float* per_loss = (float*)d_ws;                          // 128 B
    float* em       = (float*)((char*)d_ws + 256);           // 16 MB table
    const size_t need = 256 + (size_t)Nb * Tt * Lpad * sizeof(float);

    if (ws_size >= need) {
        // Fast path: full-machine gather pre-pass + cheap recursion.
        ctc_gather_kernel<<<Nb * Tt, 256, 0, stream>>>(lp, tgt, tlen, em);
        ctc_alpha_em_kernel<<<Nb, 256, 0, stream>>>(em, tgt, ilen, tlen, per_loss);
    } else {
        // Fallback: fused gather+recursion (32 blocks).
        ctc_alpha_fused_kernel<<<Nb, 256, 0, stream>>>(lp, tgt, ilen, tlen, per_loss);
    }
    ctc_finalize_kernel<<<1, 64, 0, stream>>>(per_loss, out);
}

// Round 3
// 527.599 us; speedup vs baseline: 1.1750x; 1.1750x over previous
//
#include <hip/hip_runtime.h>
#include <cstdint>
#include <cmath>

// Problem constants (from reference): T=512, N=32, C=5000, S=100
#define Tt   512
#define Nb   32
#define Cc   5000
#define Sm   100
#define Lw   201              // 2*S+1 extended lattice width
#define Lpad 256              // padded lattice width for em table
#define NEGV (-1e30f)

// ---------------------------------------------------------------------------
// logsumexp helpers (natural log). Max term contributes exactly 1.0 so only
// the non-max terms need v_exp_f32.
// ---------------------------------------------------------------------------
__device__ __forceinline__ float lse2(float a, float b) {
    float m = fmaxf(a, b);
    return m + __logf(1.0f + __expf(fminf(a, b) - m));
}
__device__ __forceinline__ float lse3(float a, float b, float c) {
    float m   = fmaxf(fmaxf(a, b), c);                 // v_max3
    float mid = __builtin_amdgcn_fmed3f(a, b, c);      // v_med3
    float lo  = fminf(fminf(a, b), c);                 // v_min3
    return m + __logf(1.0f + __expf(mid - m) + __expf(lo - m));
}

// ---------------------------------------------------------------------------
// Kernel 1: full-machine emission gather.
//   em[n][t][l] = lp[t][n][ext[n][l]]  (l even -> blank col 0, odd -> label)
// One block per (n,t): 16384 blocks -> all 256 CUs issue the scattered reads.
// ---------------------------------------------------------------------------
__global__ __launch_bounds__(256, 1)
void ctc_gather_kernel(const float* __restrict__ lp,    // [T,N,C]
                       const int*   __restrict__ tgt,   // [N,S]
                       const int*   __restrict__ tlen,  // [N]
                       float*       __restrict__ em)    // [N,T,Lpad]
{
    const int bid = blockIdx.x;          // = n*Tt + t
    const int n   = bid >> 9;            // Tt = 512 = 2^9
    const int t   = bid & (Tt - 1);
    const int l   = threadIdx.x;

    const int Lact = 2 * tlen[n] + 1;    // <= 201

    float v = NEGV;
    if (l < Lact) {
        int e = 0;                                        // blank column
        if (l & 1) e = tgt[n * Sm + ((l - 1) >> 1)];      // label column
        v = lp[((size_t)t * Nb + n) * Cc + e];
    }
    em[((size_t)bid << 8) | l] = v;      // (n*Tt+t)*Lpad + l, coalesced
}

// ---------------------------------------------------------------------------
// Kernel 2: alpha recursion — ONE WAVE per batch item, zero LDS, zero
// barriers. Lane i owns cells 4i..4i+3 in registers. Only cross-lane value
// needed per step is cell 4i-1 (prev lane's a3): one __shfl_up.
// Even (blank) cells never skip -> 2-term lse; odd cells -> 3-term lse.
// ---------------------------------------------------------------------------
__global__ __launch_bounds__(64, 1)
void ctc_alpha_wave_kernel(const float* __restrict__ em,    // [N,T,Lpad]
                           const int*   __restrict__ tgt,   // [N,S]
                           const int*   __restrict__ ilen,  // [N]
                           const int*   __restrict__ tlen,  // [N]
                           float*       __restrict__ per_loss) // [N]
{
    const int n = blockIdx.x;
    const int i = threadIdx.x;           // lane 0..63

    const int tl   = tlen[n];
    const int il   = ilen[n];
    const int Lact = 2 * tl + 1;

    // cells c0=4i (blank), c1=4i+1 (label j1=2i), c2=4i+2 (blank), c3=4i+3
    // (label j3=2i+1)
    const int  c0 = 4 * i;
    const bool in0 = (c0     < Lact);
    const bool in1 = (c0 + 1 < Lact);
    const bool in2 = (c0 + 2 < Lact);
    const bool in3 = (c0 + 3 < Lact);

    // skip-transition flags for the odd cells (label differs from label-1)
    const int j1 = 2 * i, j3 = 2 * i + 1;
    bool s1 = false, s3 = false;
    if (j1 >= 1 && j1 < Sm) s1 = (tgt[n * Sm + j1] != tgt[n * Sm + j1 - 1]);
    if (j3 >= 1 && j3 < Sm) s3 = (tgt[n * Sm + j3] != tgt[n * Sm + j3 - 1]);

    const float4* emv = (const float4*)em + ((size_t)n << 15);  // n*T*64

    // ---- t = 0 init: only cells 0 and 1 are live ----
    float4 E0 = emv[i];
    float a0 = (i == 0)            ? E0.x : NEGV;
    float a1 = (i == 0 && tl > 0)  ? E0.y : NEGV;
    float a2 = NEGV;
    float a3 = NEGV;

    // ---- register prefetch pipeline: em rows for t = 1..PF ----
    constexpr int PF = 4;
    float4 ebuf[PF];
#pragma unroll
    for (int k = 0; k < PF; ++k) {
        int t = 1 + k;
        ebuf[k] = (t < Tt) ? emv[(t << 6) + i]
                           : make_float4(NEGV, NEGV, NEGV, NEGV);
    }

    for (int tb = 1; tb < Tt; tb += PF) {
#pragma unroll
        for (int k = 0; k < PF; ++k) {       // static ebuf index (rule #20)
            const int t = tb + k;
            if (t < Tt) {
                float4 e  = ebuf[k];
                int    tp = t + PF;
                if (tp < Tt) ebuf[k] = emv[(tp << 6) + i];   // prefetch ahead

                // cell 4i-1 from previous lane (lane 0 -> NEG via guard)
                float p3  = __shfl_up(a3, 1);
                float am0 = (i > 0) ? p3 : NEGV;

                float n0 = lse2(a0, am0)                    + e.x;
                float n1 = lse3(a1, a0, s1 ? p3 : NEGV)     + e.y;
                float n2 = lse2(a2, a1)                     + e.z;
                float n3 = lse3(a3, a2, s3 ? a1 : NEGV)     + e.w;

                n0 = in0 ? n0 : NEGV;        // pos_mask
                n1 = in1 ? n1 : NEGV;
                n2 = in2 ? n2 : NEGV;
                n3 = in3 ? n3 : NEGV;

                if (t < il) {                // freeze past input length
                    a0 = n0; a1 = n1; a2 = n2; a3 = n3;
                }
            }
        }
    }

    // ---- per-n loss: cells 2*tl and 2*tl-1 of final alpha ----
    const int lb = 2 * tl;
    const int lv = (lb - 1 >= 0) ? lb - 1 : 0;

    // uniform component select, then broadcast from owning lane
    int cb = lb & 3;
    float vb = (cb == 0) ? a0 : (cb == 1) ? a1 : (cb == 2) ? a2 : a3;
    float ab = __shfl(vb, lb >> 2);
    int cl = lv & 3;
    float vl = (cl == 0) ? a0 : (cl == 1) ? a1 : (cl == 2) ? a2 : a3;
    float al = __shfl(vl, lv >> 2);

    if (i == 0) {
        float m    = fmaxf(ab, al);
        float ll   = m + __logf(__expf(ab - m) + __expf(al - m));
        float loss = -ll;
        if (!(isfinite(loss) && loss < 1e29f)) loss = 0.0f;  // zero_infinity
        int   d    = (tl >= 1) ? tl : 1;
        per_loss[n] = loss / (float)d;
    }
}

// Mean over N per-item losses -> scalar
__global__ void ctc_finalize_kernel(const float* __restrict__ per_loss,
                                    float* __restrict__ out)
{
    int i = threadIdx.x;
    float v = (i < Nb) ? per_loss[i] : 0.0f;
#pragma unroll
    for (int off = 32; off > 0; off >>= 1)
        v += __shfl_down(v, off, 64);
    if (i == 0) out[0] = v * (1.0f / Nb);
}

extern "C" void kernel_launch(void* const* d_in, const int* in_sizes, int n_in,
                              void* d_out, int out_size, void* d_ws, size_t ws_size,
                              hipStream_t stream)
{
    const float* lp   = (const float*)d_in[0];   // [T,N,C] f32
    const int*   tgt  = (const int*)  d_in[1];   // [N,S]   i32
    const int*   ilen = (const int*)  d_in[2];   // [N]     i32
    const int*   tlen = (const int*)  d_in[3];   // [N]     i32
    float*       out  = (float*)d_out;           // scalar f32

    float* per_loss = (float*)d_ws;                          // 128 B
    float* em       = (float*)((char*)d_ws + 256);           // 16 MB table

    ctc_gather_kernel<<<Nb * Tt, 256, 0, stream>>>(lp, tgt, tlen, em);
    ctc_alpha_wave_kernel<<<Nb, 64, 0, stream>>>(em, tgt, ilen, tlen, per_loss);
    ctc_finalize_kernel<<<1, 64, 0, stream>>>(per_loss, out);
}

// Round 7
// 522.075 us; speedup vs baseline: 1.1874x; 1.0106x over previous
//
#include <hip/hip_runtime.h>
#include <cstdint>
#include <cmath>

// Problem constants (from reference): T=512, N=32, C=5000, S=100
#define Tt   512
#define Nb   32
#define Cc   5000
#define Sm   100
#define Lw   201              // 2*S+1 extended lattice width
#define Lpad 256              // padded lattice width for em table
#define NEGV (-1e30f)
#define TCH  8                // t-steps per gather block (8-way MLP)

// ---------------------------------------------------------------------------
// logsumexp helpers (natural log). Max term contributes exactly 1.0 so only
// the non-max terms need v_exp_f32.
// ---------------------------------------------------------------------------
__device__ __forceinline__ float lse2(float a, float b) {
    float m = fmaxf(a, b);
    return m + __logf(1.0f + __expf(fminf(a, b) - m));
}
__device__ __forceinline__ float lse3(float a, float b, float c) {
    float m   = fmaxf(fmaxf(a, b), c);                 // v_max3
    float mid = __builtin_amdgcn_fmed3f(a, b, c);      // v_med3
    float lo  = fminf(fminf(a, b), c);                 // v_min3
    return m + __logf(1.0f + __expf(mid - m) + __expf(lo - m));
}

// ---------------------------------------------------------------------------
// Kernel 1: full-machine emission gather, TCH t-steps per block.
//   em[n][t][l] = lp[t][n][ext[n][l]]  (l even -> blank col 0, odd -> label)
// 2048 blocks x 256 threads; each thread issues TCH INDEPENDENT scattered
// loads (8-way MLP — round-2's 1 dependent load/thread was latency-bound at
// ~0.6 TB/s), tgt/tlen read once per block. Stores coalesced (1KB per t).
// ---------------------------------------------------------------------------
__global__ __launch_bounds__(256, 1)
void ctc_gather_kernel(const float* __restrict__ lp,    // [T,N,C]
                       const int*   __restrict__ tgt,   // [N,S]
                       const int*   __restrict__ tlen,  // [N]
                       float*       __restrict__ em)    // [N,T,Lpad]
{
    const int bid = blockIdx.x;          // = n*(Tt/TCH) + tc
    const int n   = bid >> 6;            // Tt/TCH = 64
    const int t0  = (bid & 63) * TCH;
    const int l   = threadIdx.x;

    const int Lact = 2 * tlen[n] + 1;    // <= 201

    int e = 0;                                            // blank column
    if (l & 1) {
        int j = (l - 1) >> 1;
        if (j < Sm) e = tgt[n * Sm + j];                  // label column
    }
    const bool live = (l < Lact);

    const float* src = lp + (size_t)n * Cc + e;           // + t*(Nb*Cc)
    float v[TCH];
#pragma unroll
    for (int k = 0; k < TCH; ++k)                         // 8 loads in flight
        v[k] = live ? src[(size_t)(t0 + k) * (Nb * Cc)] : NEGV;

    float* dst = em + (((size_t)n * Tt + t0) << 8) + l;   // [n][t0+k][l]
#pragma unroll
    for (int k = 0; k < TCH; ++k)
        dst[k << 8] = v[k];
}

// ---------------------------------------------------------------------------
// Kernel 2: alpha recursion — ONE WAVE per batch item, zero LDS, zero
// barriers. Lane i owns cells 4i..4i+3 in registers; only cross-lane value
// per step is cell 4i-1 (prev lane's a3): one __shfl_up, which feeds only
// n0/n1 — the a3->a3 chain (next step's shfl source) is shfl-free, so the
// critical path is a single lse3 (~50-60 cy/step).
// Per-step pos_mask dropped: cells >= Lact read only lower-indexed cells,
// accumulate ~-1e30/step (finite at T=512: ~-5e32; exp -> 0), and are never
// read by live cells or the readout -> output-identical to the reference.
// em reads register-prefetched PF=16 deep (statically indexed, rule #20):
// ~16 steps x ~50 cy = 800 cy of lookahead, covering the full L3/HBM
// latency that limited round 3's PF=4 version (~660 cy/step observed).
// ---------------------------------------------------------------------------
__global__ __launch_bounds__(64, 1)
void ctc_alpha_wave_kernel(const float* __restrict__ em,    // [N,T,Lpad]
                           const int*   __restrict__ tgt,   // [N,S]
                           const int*   __restrict__ ilen,  // [N]
                           const int*   __restrict__ tlen,  // [N]
                           float*       __restrict__ per_loss) // [N]
{
    const int n = blockIdx.x;
    const int i = threadIdx.x;           // lane 0..63

    const int tl = tlen[n];
    const int il = ilen[n];

    // skip-transition flags for the odd cells (label differs from label-1)
    const int j1 = 2 * i, j3 = 2 * i + 1;
    bool s1 = false, s3 = false;
    if (j1 >= 1 && j1 < Sm) s1 = (tgt[n * Sm + j1] != tgt[n * Sm + j1 - 1]);
    if (j3 >= 1 && j3 < Sm) s3 = (tgt[n * Sm + j3] != tgt[n * Sm + j3 - 1]);

    const float4* emv = (const float4*)em + ((size_t)n << 15);  // n*T*64

    // ---- t = 0 init: only cells 0 and 1 are live ----
    float4 E0 = emv[i];
    float a0 = (i == 0)           ? E0.x : NEGV;
    float a1 = (i == 0 && tl > 0) ? E0.y : NEGV;
    float a2 = NEGV;
    float a3 = NEGV;

    // ---- register prefetch pipeline: em rows for t = 1..PF ----
    constexpr int PF = 16;
    float4 ebuf[PF];
#pragma unroll
    for (int k = 0; k < PF; ++k) {
        int t = 1 + k;
        ebuf[k] = (t < Tt) ? emv[(t << 6) + i]
                           : make_float4(NEGV, NEGV, NEGV, NEGV);
    }

    for (int tb = 1; tb < Tt; tb += PF) {
#pragma unroll
        for (int k = 0; k < PF; ++k) {       // static ebuf index (rule #20)
            const int t = tb + k;
            if (t < Tt) {                    // block-uniform guard
                float4 e  = ebuf[k];
                int    tp = t + PF;
                if (tp < Tt) ebuf[k] = emv[(tp << 6) + i];   // prefetch ahead

                // cell 4i-1 from previous lane (lane 0 -> NEG via guard)
                float p3  = __shfl_up(a3, 1);
                float am0 = (i > 0) ? p3 : NEGV;

                float n0 = lse2(a0, am0)                + e.x;
                float n1 = lse3(a1, a0, s1 ? p3 : NEGV) + e.y;
                float n2 = lse2(a2, a1)                 + e.z;
                float n3 = lse3(a3, a2, s3 ? a1 : NEGV) + e.w;

                if (t < il) {                // freeze past input length
                    a0 = n0; a1 = n1; a2 = n2; a3 = n3;
                }
            }
        }
    }

    // ---- per-n loss: cells 2*tl and 2*tl-1 of final alpha ----
    const int lb = 2 * tl;
    const int lv = (lb - 1 >= 0) ? lb - 1 : 0;

    int   cb = lb & 3;
    float vb = (cb == 0) ? a0 : (cb == 1) ? a1 : (cb == 2) ? a2 : a3;
    float ab = __shfl(vb, lb >> 2);
    int   cl = lv & 3;
    float vl = (cl == 0) ? a0 : (cl == 1) ? a1 : (cl == 2) ? a2 : a3;
    float al = __shfl(vl, lv >> 2);

    if (i == 0) {
        float m    = fmaxf(ab, al);
        float ll   = m + __logf(__expf(ab - m) + __expf(al - m));
        float loss = -ll;
        if (!(isfinite(loss) && loss < 1e29f)) loss = 0.0f;  // zero_infinity
        int   d    = (tl >= 1) ? tl : 1;
        per_loss[n] = loss / (float)d;
    }
}

// Mean over N per-item losses -> scalar
__global__ void ctc_finalize_kernel(const float* __restrict__ per_loss,
                                    float* __restrict__ out)
{
    int i = threadIdx.x;
    float v = (i < Nb) ? per_loss[i] : 0.0f;
#pragma unroll
    for (int off = 32; off > 0; off >>= 1)
        v += __shfl_down(v, off, 64);
    if (i == 0) out[0] = v * (1.0f / Nb);
}

extern "C" void kernel_launch(void* const* d_in, const int* in_sizes, int n_in,
                              void* d_out, int out_size, void* d_ws, size_t ws_size,
                              hipStream_t stream)
{
    const float* lp   = (const float*)d_in[0];   // [T,N,C] f32
    const int*   tgt  = (const int*)  d_in[1];   // [N,S]   i32
    const int*   ilen = (const int*)  d_in[2];   // [N]     i32
    const int*   tlen = (const int*)  d_in[3];   // [N]     i32
    float*       out  = (float*)d_out;           // scalar f32

    float* per_loss = (float*)d_ws;                          // 128 B
    float* em       = (float*)((char*)d_ws + 256);           // 16 MB table

    ctc_gather_kernel<<<Nb * (Tt / TCH), 256, 0, stream>>>(lp, tgt, tlen, em);
    ctc_alpha_wave_kernel<<<Nb, 64, 0, stream>>>(em, tgt, ilen, tlen, per_loss);
    ctc_finalize_kernel<<<1, 64, 0, stream>>>(per_loss, out);
}

// Round 11
// 491.923 us; speedup vs baseline: 1.2602x; 1.0613x over previous
//
#include <hip/hip_runtime.h>
#include <cstdint>
#include <cmath>

// Problem constants (from reference): T=512, N=32, C=5000, S=100
#define Tt   512
#define Nb   32
#define Cc   5000
#define Sm   100
#define NEGV (-1e30f)          // log-domain -inf surrogate (any base)
#define LOG2E 1.4426950408889634f
#define LN2   0.6931471805599453f
#define TCH  8                 // t-steps per gather block

// Native 2^x / log2(x). NOTE: __exp2f/__log2f do NOT exist in HIP device
// code (glibc math.h declares them host-side -> round-9 compile failure).
// __builtin_amdgcn_exp2f/logf are the raw v_exp_f32/v_log_f32 builtins.
#if __has_builtin(__builtin_amdgcn_exp2f)
#define EXP2F(x) __builtin_amdgcn_exp2f(x)
#else
#define EXP2F(x) exp2f(x)
#endif
#if __has_builtin(__builtin_amdgcn_logf)
#define LOG2F(x) __builtin_amdgcn_logf(x)
#else
#define LOG2F(x) log2f(x)
#endif

// All lattice math in LOG2 domain: gather pre-scales emissions by LOG2E so
// v_exp_f32 (=2^x) / v_log_f32 (=log2 x) need no base-conversion multiplies.
__device__ __forceinline__ float lse2_l2(float a, float b) {
    float m = fmaxf(a, b);
    return m + LOG2F(1.0f + EXP2F(fminf(a, b) - m));
}
__device__ __forceinline__ float lse3_l2(float a, float b, float c) {
    float m   = fmaxf(fmaxf(a, b), c);                 // v_max3
    float mid = __builtin_amdgcn_fmed3f(a, b, c);      // v_med3
    float lo  = fminf(fminf(a, b), c);                 // v_min3
    return m + LOG2F(1.0f + EXP2F(mid - m) + EXP2F(lo - m));
}

// ---------------------------------------------------------------------------
// Kernel 1: gather ONLY the 100 odd-cell (label) emissions per (n,t) into
// em2[N][T][128] (pad 100..127 = NEGV), and the blank emission into bl[N][T].
// Blank cells (101 of 201) all share lp[t][n][0] -> never materialized
// per-cell (halves scattered loads and em writes vs round 7).
// 2048 blocks x 128 threads; TCH independent scattered loads per thread.
// ---------------------------------------------------------------------------
__global__ __launch_bounds__(128, 1)
void ctc_gather_kernel(const float* __restrict__ lp,    // [T,N,C]
                       const int*   __restrict__ tgt,   // [N,S]
                       float*       __restrict__ em2,   // [N,T,128] log2-dom
                       float*       __restrict__ bl)    // [N,T]     log2-dom
{
    const int bid = blockIdx.x;          // = n*(Tt/TCH) + tc
    const int n   = bid >> 6;            // Tt/TCH = 64
    const int t0  = (bid & 63) * TCH;
    const int j   = threadIdx.x;         // 0..127

    float* dst = em2 + (((size_t)n * Tt + t0) << 7) + j;   // [n][t0+k][j]

    if (j < Sm) {
        const int e = tgt[n * Sm + j];                     // label column
        const float* src = lp + (size_t)n * Cc + e;        // + t*(Nb*Cc)
        float v[TCH];
#pragma unroll
        for (int k = 0; k < TCH; ++k)                      // 8 loads in flight
            v[k] = src[(size_t)(t0 + k) * (Nb * Cc)];
#pragma unroll
        for (int k = 0; k < TCH; ++k)
            dst[k << 7] = v[k] * LOG2E;
    } else {
#pragma unroll
        for (int k = 0; k < TCH; ++k)                      // pad columns
            dst[k << 7] = NEGV;
        if (j < Sm + TCH) {                                // blanks: 8 threads
            int k = j - Sm;
            bl[n * Tt + t0 + k] =
                lp[(size_t)(t0 + k) * (Nb * Cc) + (size_t)n * Cc] * LOG2E;
        }
    }
}

// ---------------------------------------------------------------------------
// Kernel 2: alpha recursion — ONE WAVE per batch item, zero LDS/barriers.
// Lane i owns cells 4i..4i+3; cross-lane need per step = cell 4i-1 (prev
// lane's a3) via one ds_bpermute. Blank emission comes from a wave-uniform
// bl[n][t] read (broadcast; 64B line serves 16 steps from L1) — even cells
// need no per-cell emission load. Odd-cell emissions: one float2/lane.
// Round-7 post-mortem: alpha is EXECUTION-bound (~660cy/step), not latency-
// bound, so this version attacks instructions/step (~75 -> ~46): log2
// domain (no LOG2E muls), no redundant even-cell values, PF=8.
// Dead cells (>= Lact) decay at ~-1e30/step: finite at T=512 (~-5e32),
// exp2 -> 0, never read by live cells or readout -> output-identical.
// ---------------------------------------------------------------------------
__global__ __launch_bounds__(64, 1)
void ctc_alpha_wave_kernel(const float* __restrict__ em2,   // [N,T,128]
                           const float* __restrict__ bl,    // [N,T]
                           const int*   __restrict__ tgt,   // [N,S]
                           const int*   __restrict__ ilen,  // [N]
                           const int*   __restrict__ tlen,  // [N]
                           float*       __restrict__ per_loss) // [N]
{
    const int n = blockIdx.x;
    const int i = threadIdx.x;           // lane 0..63

    const int tl = tlen[n];
    const int il = ilen[n];

    // skip flags for odd cells 4i+1 (label j1=2i) and 4i+3 (label j3=2i+1)
    const int j1 = 2 * i, j3 = 2 * i + 1;
    bool s1 = false, s3 = false;
    if (j1 >= 1 && j1 < Sm) s1 = (tgt[n * Sm + j1] != tgt[n * Sm + j1 - 1]);
    if (j3 < Sm)            s3 = (tgt[n * Sm + j3] != tgt[n * Sm + j3 - 1]);

    const float2* e2 = (const float2*)em2 + ((size_t)n << 15);  // n*T*64
    const float*  bn = bl + n * Tt;

    // bpermute byte address for "value from lane i-1" (precomputed once)
    const int pull = (i > 0 ? i - 1 : 0) << 2;

    // ---- t = 0 init: only cells 0 and 1 live ----
    float2 E0 = e2[i];
    float a0 = (i == 0)           ? bn[0] : NEGV;
    float a1 = (i == 0 && tl > 0) ? E0.x  : NEGV;
    float a2 = NEGV;
    float a3 = NEGV;

    // ---- register prefetch: em2 float2 rows for t = 1..PF ----
    constexpr int PF = 8;
    float2 ebuf[PF];
#pragma unroll
    for (int k = 0; k < PF; ++k) {
        int t = 1 + k;
        ebuf[k] = (t < Tt) ? e2[(t << 6) + i] : make_float2(NEGV, NEGV);
    }

    for (int tb = 1; tb < Tt; tb += PF) {
#pragma unroll
        for (int k = 0; k < PF; ++k) {       // static ebuf index (rule #20)
            const int t = tb + k;
            if (t < Tt) {                    // block-uniform guard
                float2 e  = ebuf[k];
                float  eb = bn[t];           // wave-uniform blank (broadcast)
                int    tp = t + PF;
                if (tp < Tt) ebuf[k] = e2[(tp << 6) + i];   // prefetch

                float p3  = __int_as_float(
                    __builtin_amdgcn_ds_bpermute(pull, __float_as_int(a3)));
                float am0 = (i > 0) ? p3 : NEGV;

                float n0 = lse2_l2(a0, am0)                   + eb;
                float n1 = lse3_l2(a1, a0, s1 ? p3 : NEGV)    + e.x;
                float n2 = lse2_l2(a2, a1)                    + eb;
                float n3 = lse3_l2(a3, a2, s3 ? a1 : NEGV)    + e.y;

                if (t < il) {                // freeze past input length
                    a0 = n0; a1 = n1; a2 = n2; a3 = n3;
                }
            }
        }
    }

    // ---- per-n loss: cells 2*tl and 2*tl-1 of final alpha (log2 -> nat) --
    const int lb = 2 * tl;
    const int lv = (lb - 1 >= 0) ? lb - 1 : 0;

    int   cb = lb & 3;
    float vb = (cb == 0) ? a0 : (cb == 1) ? a1 : (cb == 2) ? a2 : a3;
    float ab = __shfl(vb, lb >> 2);
    int   cl = lv & 3;
    float vl = (cl == 0) ? a0 : (cl == 1) ? a1 : (cl == 2) ? a2 : a3;
    float al = __shfl(vl, lv >> 2);

    if (i == 0) {
        float m    = fmaxf(ab, al);
        float ll2  = m + LOG2F(EXP2F(ab - m) + EXP2F(al - m));
        float loss = -ll2 * LN2;             // back to natural log
        if (!(isfinite(loss) && loss < 1e29f)) loss = 0.0f;  // zero_infinity
        int   d    = (tl >= 1) ? tl : 1;
        per_loss[n] = loss / (float)d;
    }
}

// Mean over N per-item losses -> scalar
__global__ void ctc_finalize_kernel(const float* __restrict__ per_loss,
                                    float* __restrict__ out)
{
    int i = threadIdx.x;
    float v = (i < Nb) ? per_loss[i] : 0.0f;
#pragma unroll
    for (int off = 32; off > 0; off >>= 1)
        v += __shfl_down(v, off, 64);
    if (i == 0) out[0] = v * (1.0f / Nb);
}

extern "C" void kernel_launch(void* const* d_in, const int* in_sizes, int n_in,
                              void* d_out, int out_size, void* d_ws, size_t ws_size,
                              hipStream_t stream)
{
    const float* lp   = (const float*)d_in[0];   // [T,N,C] f32
    const int*   tgt  = (const int*)  d_in[1];   // [N,S]   i32
    const int*   ilen = (const int*)  d_in[2];   // [N]     i32
    const int*   tlen = (const int*)  d_in[3];   // [N]     i32
    float*       out  = (float*)d_out;           // scalar f32

    // ws layout: per_loss[0..] (256B) | bl[N*T] (64KB) | em2[N*T*128] (8MB)
    float* per_loss = (float*)d_ws;
    float* bl       = (float*)((char*)d_ws + 256);
    float* em2      = (float*)((char*)d_ws + 256 + (size_t)Nb * Tt * 4);

    ctc_gather_kernel<<<Nb * (Tt / TCH), 128, 0, stream>>>(lp, tgt, em2, bl);
    ctc_alpha_wave_kernel<<<Nb, 64, 0, stream>>>(em2, bl, tgt, ilen, tlen, per_loss);
    ctc_finalize_kernel<<<1, 64, 0, stream>>>(per_loss, out);
}

// Round 12
// 480.128 us; speedup vs baseline: 1.2912x; 1.0246x over previous
//
#include <hip/hip_runtime.h>
#include <cstdint>
#include <cmath>

// Problem constants (from reference): T=512, N=32, C=5000, S=100
#define Tt   512
#define Nb   32
#define Cc   5000
#define Sm   100
#define NEGV (-1e30f)          // log-domain -inf surrogate (any base)
#define LOG2E 1.4426950408889634f
#define LN2   0.6931471805599453f
#define TCH  8                 // t-steps per gather block

// Native 2^x / log2(x). __exp2f/__log2f do NOT exist device-side (glibc
// host decls caused round-9 compile failure); guarded builtins instead.
#if __has_builtin(__builtin_amdgcn_exp2f)
#define EXP2F(x) __builtin_amdgcn_exp2f(x)
#else
#define EXP2F(x) exp2f(x)
#endif
#if __has_builtin(__builtin_amdgcn_logf)
#define LOG2F(x) __builtin_amdgcn_logf(x)
#else
#define LOG2F(x) log2f(x)
#endif

// All lattice math in LOG2 domain (emissions pre-scaled by log2(e) in the
// gather; lse is scale-equivariant so alpha = log2(e) * alpha_nat exactly).
__device__ __forceinline__ float lse2_l2(float a, float b) {
    float m = fmaxf(a, b);
    return m + LOG2F(1.0f + EXP2F(fminf(a, b) - m));
}
__device__ __forceinline__ float lse3_l2(float a, float b, float c) {
    float m   = fmaxf(fmaxf(a, b), c);                 // v_max3
    float mid = __builtin_amdgcn_fmed3f(a, b, c);      // v_med3
    float lo  = fminf(fminf(a, b), c);                 // v_min3
    return m + LOG2F(1.0f + EXP2F(mid - m) + EXP2F(lo - m));
}

// ---------------------------------------------------------------------------
// Kernel 1: full-machine gather. em2[n][t][0..99] = label emissions,
// em2[n][t][100] = BLANK emission (rides in the same row -> alpha needs no
// separate blank array/load; lane 50's float2.x IS the blank), 101..127 pad.
// 2048 blocks x 128 threads; TCH independent scattered loads per thread.
// Also zeroes out[0] for alpha's atomicAdd finalize (stream-ordered).
// ---------------------------------------------------------------------------
__global__ __launch_bounds__(128, 1)
void ctc_gather_kernel(const float* __restrict__ lp,    // [T,N,C]
                       const int*   __restrict__ tgt,   // [N,S]
                       float*       __restrict__ em2,   // [N,T,128] log2-dom
                       float*       __restrict__ out)   // [1] (init to 0)
{
    const int bid = blockIdx.x;          // = n*(Tt/TCH) + tc
    const int n   = bid >> 6;            // Tt/TCH = 64
    const int t0  = (bid & 63) * TCH;
    const int j   = threadIdx.x;         // 0..127

    if (bid == 0 && j == 127) out[0] = 0.0f;   // d_out re-poisoned each call

    float* dst = em2 + (((size_t)n * Tt + t0) << 7) + j;   // [n][t0+k][j]

    if (j <= Sm) {                                        // labels + blank
        const int e = (j < Sm) ? tgt[n * Sm + j] : 0;     // col 100 -> blank
        const float* src = lp + (size_t)n * Cc + e;       // + t*(Nb*Cc)
        float v[TCH];
#pragma unroll
        for (int k = 0; k < TCH; ++k)                     // 8 loads in flight
            v[k] = src[(size_t)(t0 + k) * (Nb * Cc)];
#pragma unroll
        for (int k = 0; k < TCH; ++k)
            dst[k << 7] = v[k] * LOG2E;
    } else {
#pragma unroll
        for (int k = 0; k < TCH; ++k)                     // pad columns
            dst[k << 7] = NEGV;
    }
}

// ---------------------------------------------------------------------------
// Kernel 2: alpha recursion — ONE WAVE per batch item, zero LDS/barriers,
// and (new) ZERO per-step memory ops beyond the one prefetched float2:
// the blank emission is extracted from lane 50's e.x via v_readlane (the
// round-11 per-step bl[n][t] load and its uncovered latency are gone).
// Lane i owns cells 4i..4i+3; cross-lane need = cell 4i-1 via ds_bpermute.
// Dead cells (>= Lact) may creep alive with blank emissions, but live cells
// and the readout only read lower-indexed cells -> output-identical.
// Finalize fused: per-block atomicAdd into out[0] (zeroed by gather).
// ---------------------------------------------------------------------------
__global__ __launch_bounds__(64, 1)
void ctc_alpha_wave_kernel(const float* __restrict__ em2,   // [N,T,128]
                           const int*   __restrict__ tgt,   // [N,S]
                           const int*   __restrict__ ilen,  // [N]
                           const int*   __restrict__ tlen,  // [N]
                           float*       __restrict__ out)   // [1] accum
{
    const int n = blockIdx.x;
    const int i = threadIdx.x;           // lane 0..63

    const int tl = tlen[n];
    const int il = ilen[n];

    // skip flags for odd cells 4i+1 (label j1=2i) and 4i+3 (label j3=2i+1)
    const int j1 = 2 * i, j3 = 2 * i + 1;
    bool s1 = false, s3 = false;
    if (j1 >= 1 && j1 < Sm) s1 = (tgt[n * Sm + j1] != tgt[n * Sm + j1 - 1]);
    if (j3 < Sm)            s3 = (tgt[n * Sm + j3] != tgt[n * Sm + j3 - 1]);

    const float2* e2 = (const float2*)em2 + ((size_t)n << 15);  // n*T*64

    // bpermute byte address for "value from lane i-1" (precomputed once)
    const int pull = (i > 0 ? i - 1 : 0) << 2;

    // ---- t = 0 init: only cells 0 and 1 live ----
    float2 E0 = e2[i];                   // lane 50 holds blank in E0.x
    float b0 = __int_as_float(
        __builtin_amdgcn_readlane(__float_as_int(E0.x), 50));
    float a0 = (i == 0)           ? b0   : NEGV;
    float a1 = (i == 0 && tl > 0) ? E0.x : NEGV;
    float a2 = NEGV;
    float a3 = NEGV;

    // ---- register prefetch: em2 float2 rows for t = 1..PF ----
    constexpr int PF = 8;
    float2 ebuf[PF];
#pragma unroll
    for (int k = 0; k < PF; ++k)         // t = 1..8, always < Tt
        ebuf[k] = e2[((1 + k) << 6) + i];

    for (int tb = 1; tb < Tt; tb += PF) {
#pragma unroll
        for (int k = 0; k < PF; ++k) {       // static ebuf index (rule #20)
            const int t = tb + k;
            if (t < Tt) {                    // block-uniform guard
                float2 e  = ebuf[k];
                int    tp = t + PF;
                if (tp < Tt) ebuf[k] = e2[(tp << 6) + i];   // prefetch

                // blank emission: lane 50's e.x, broadcast in-register
                float eb = __int_as_float(
                    __builtin_amdgcn_readlane(__float_as_int(e.x), 50));

                float p3  = __int_as_float(
                    __builtin_amdgcn_ds_bpermute(pull, __float_as_int(a3)));
                float am0 = (i > 0) ? p3 : NEGV;

                float n0 = lse2_l2(a0, am0)                   + eb;
                float n1 = lse3_l2(a1, a0, s1 ? p3 : NEGV)    + e.x;
                float n2 = lse2_l2(a2, a1)                    + eb;
                float n3 = lse3_l2(a3, a2, s3 ? a1 : NEGV)    + e.y;

                if (t < il) {                // freeze past input length
                    a0 = n0; a1 = n1; a2 = n2; a3 = n3;
                }
            }
        }
    }

    // ---- per-n loss: cells 2*tl and 2*tl-1 of final alpha (log2 -> nat) --
    const int lb = 2 * tl;
    const int lv = (lb - 1 >= 0) ? lb - 1 : 0;

    int   cb = lb & 3;
    float vb = (cb == 0) ? a0 : (cb == 1) ? a1 : (cb == 2) ? a2 : a3;
    float ab = __shfl(vb, lb >> 2);
    int   cl = lv & 3;
    float vl = (cl == 0) ? a0 : (cl == 1) ? a1 : (cl == 2) ? a2 : a3;
    float al = __shfl(vl, lv >> 2);

    if (i == 0) {
        float m    = fmaxf(ab, al);
        float ll2  = m + LOG2F(EXP2F(ab - m) + EXP2F(al - m));
        float loss = -ll2 * LN2;             // back to natural log
        if (!(isfinite(loss) && loss < 1e29f)) loss = 0.0f;  // zero_infinity
        int   d    = (tl >= 1) ? tl : 1;
        atomicAdd(out, loss / ((float)d * (float)Nb));  // fused mean
    }
}

extern "C" void kernel_launch(void* const* d_in, const int* in_sizes, int n_in,
                              void* d_out, int out_size, void* d_ws, size_t ws_size,
                              hipStream_t stream)
{
    const float* lp   = (const float*)d_in[0];   // [T,N,C] f32
    const int*   tgt  = (const int*)  d_in[1];   // [N,S]   i32
    const int*   ilen = (const int*)  d_in[2];   // [N]     i32
    const int*   tlen = (const int*)  d_in[3];   // [N]     i32
    float*       out  = (float*)d_out;           // scalar f32

    // ws layout: em2[N*T*128] (8.4 MB)
    float* em2 = (float*)d_ws;

    ctc_gather_kernel<<<Nb * (Tt / TCH), 128, 0, stream>>>(lp, tgt, em2, out);
    ctc_alpha_wave_kernel<<<Nb, 64, 0, stream>>>(em2, tgt, ilen, tlen, out);
}